// Round 1
// baseline (147.746 us; speedup 1.0000x reference)
//
#include <hip/hip_runtime.h>

// Fused JPEG decompress: dequant -> 8x8 IDCT (separable, via LDS) ->
// block merge -> chroma 2x nearest upsample -> YCbCr->RGB -> clip/255.
// One 256-thread workgroup per 16x16 macroblock (4 Y blocks, 1 Cb, 1 Cr).
// Shapes fixed by setup_inputs(): B=16, h=w=1024.

#define IMG_W 1024
#define IMG_HW (1024 * 1024)

// JPEG luma quant table (row-major, x=row freq, y=col freq)
__constant__ float YTAB[64] = {
    16, 11, 10, 16, 24, 40, 51, 61,
    12, 12, 14, 19, 26, 58, 60, 55,
    14, 13, 16, 24, 40, 57, 69, 56,
    14, 17, 22, 29, 51, 87, 80, 62,
    18, 22, 37, 56, 68, 109, 103, 77,
    24, 35, 55, 64, 81, 104, 113, 92,
    49, 64, 78, 87, 103, 121, 120, 101,
    72, 92, 95, 98, 112, 100, 103, 99};

// JPEG chroma quant table
__constant__ float CTAB[64] = {
    17, 18, 24, 47, 99, 99, 99, 99,
    18, 21, 26, 66, 99, 99, 99, 99,
    24, 26, 56, 99, 99, 99, 99, 99,
    47, 66, 99, 99, 99, 99, 99, 99,
    99, 99, 99, 99, 99, 99, 99, 99,
    99, 99, 99, 99, 99, 99, 99, 99,
    99, 99, 99, 99, 99, 99, 99, 99,
    99, 99, 99, 99, 99, 99, 99, 99};

// COS8[x*8+u] = cos((2u+1)*x*pi/16)  (DCT-II basis)
__constant__ float COS8[64] = {
    1.0f,          1.0f,          1.0f,          1.0f,          1.0f,          1.0f,          1.0f,          1.0f,
    0.980785280f,  0.831469612f,  0.555570233f,  0.195090322f, -0.195090322f, -0.555570233f, -0.831469612f, -0.980785280f,
    0.923879533f,  0.382683432f, -0.382683432f, -0.923879533f, -0.923879533f, -0.382683432f,  0.382683432f,  0.923879533f,
    0.831469612f, -0.195090322f, -0.980785280f, -0.555570233f,  0.555570233f,  0.980785280f,  0.195090322f, -0.831469612f,
    0.707106781f, -0.707106781f, -0.707106781f,  0.707106781f,  0.707106781f, -0.707106781f, -0.707106781f,  0.707106781f,
    0.555570233f, -0.980785280f,  0.195090322f,  0.831469612f, -0.831469612f, -0.195090322f,  0.980785280f, -0.555570233f,
    0.382683432f, -0.923879533f,  0.923879533f, -0.382683432f, -0.382683432f,  0.923879533f, -0.923879533f,  0.382683432f,
    0.195090322f, -0.555570233f,  0.831469612f, -0.980785280f,  0.980785280f, -0.831469612f,  0.555570233f, -0.195090322f};

__global__ __launch_bounds__(256) void jpeg_decode_kernel(
    const float* __restrict__ yq, const float* __restrict__ cbq,
    const float* __restrict__ crq, const float* __restrict__ fac,
    float* __restrict__ out)
{
    // LDS: 6 blocks (4 Y + cb + cr) of scaled coeffs, stage-1 results,
    // and the final chroma pixel tile. Total 3.5 KB.
    __shared__ float sco[6][64];   // scaled (dequantized) coefficients
    __shared__ float tmp[6][64];   // stage-1 output, stored TRANSPOSED: tmp[blk][v*8+x]
    __shared__ float cpix[2][64];  // chroma IDCT pixels (no +128; cancels color shift)

    const int t  = threadIdx.x;
    const int b  = blockIdx.y;
    const int mb = blockIdx.x;          // macroblock id in 64x64 grid
    const int my = mb >> 6, mx = mb & 63;
    const int wv = t >> 6;              // wave id == Y block id within macroblock
    const int l  = t & 63;
    const int lx = l >> 3, lv = l & 7;  // (freq-row / pixel-row, freq-col / pixel-col)

    const float factor = fac[0];

    // Per-thread cosine columns (register-resident; avoids per-FMA LDS gathers)
    float cv[8], cu[8];
#pragma unroll
    for (int k = 0; k < 8; ++k) {
        cv[k] = COS8[k * 8 + lv];  // cos_t[k][v]
        cu[k] = COS8[k * 8 + lx];  // cos_t[k][u]
    }

    // ---- load + dequantize (fold 0.25 * alpha * table * factor) ----
    {
        const float ax = (lx == 0) ? 0.70710678118654752f : 1.0f;
        const float ay = (lv == 0) ? 0.70710678118654752f : 1.0f;
        const float am = 0.25f * ax * ay * factor;

        const int dy = wv >> 1, dx = wv & 1;
        const int n  = (my * 2 + dy) * 128 + (mx * 2 + dx);  // Y block index in 128x128 grid
        const float v = yq[((size_t)(b * 16384 + n) << 6) + l];
        sco[wv][l] = v * (YTAB[l] * am);

        if (t < 128) {
            const int p  = t >> 6;                 // 0 = cb, 1 = cr
            const int nc = (my << 6) | mx;         // chroma block index in 64x64 grid
            const float* src = p ? crq : cbq;
            const float cvl = src[((size_t)(b * 4096 + nc) << 6) + l];
            sco[4 + p][l] = cvl * (CTAB[l] * am);
        }
    }
    __syncthreads();

    // ---- IDCT stage 1: contract freq-col y -> pixel-col v ----
    // thread (x=lx, v=lv): t1[x][v] = sum_y sco[x][y] * cos_t[y][v]; store transposed.
    {
        float acc = 0.f;
#pragma unroll
        for (int k = 0; k < 8; ++k) acc += sco[wv][lx * 8 + k] * cv[k];
        tmp[wv][lv * 8 + lx] = acc;
        if (t < 128) {
            const int p = t >> 6;
            float acc2 = 0.f;
#pragma unroll
            for (int k = 0; k < 8; ++k) acc2 += sco[4 + p][lx * 8 + k] * cv[k];
            tmp[4 + p][lv * 8 + lx] = acc2;
        }
    }
    __syncthreads();

    // ---- IDCT stage 2: contract freq-row x -> pixel-row u ----
    // thread (u=lx, v=lv): out[u][v] = sum_x t1[x][v] * cos_t[x][u]
    float ypix;
    {
        float acc = 0.f;
#pragma unroll
        for (int k = 0; k < 8; ++k) acc += tmp[wv][lv * 8 + k] * cu[k];
        ypix = acc + 128.0f;
        if (t < 128) {
            const int p = t >> 6;
            float acc2 = 0.f;
#pragma unroll
            for (int k = 0; k < 8; ++k) acc2 += tmp[4 + p][lv * 8 + k] * cu[k];
            cpix[p][l] = acc2;  // chroma: +128 cancels with COLOR_SHIFT -128
        }
    }
    __syncthreads();

    // ---- chroma upsample (nearest 2x) + YCbCr->RGB + clip/255 + store ----
    {
        const int dy = wv >> 1, dx = wv & 1;
        const int ty = dy * 8 + lx, tx = dx * 8 + lv;       // pixel within 16x16 tile
        const int ci = ((ty >> 1) << 3) | (tx >> 1);        // chroma pixel index
        const float cbv = cpix[0][ci];
        const float crv = cpix[1][ci];

        float R = ypix + 1.402f * crv;
        float G = ypix - 0.344136f * cbv - 0.714136f * crv;
        float B = ypix + 1.772f * cbv;

        const int gy = my * 16 + ty, gx = mx * 16 + tx;
        const size_t base = (size_t)b * 3 * IMG_HW + (size_t)gy * IMG_W + gx;
        out[base]              = fminf(fmaxf(R, 0.f), 255.f) * (1.0f / 255.0f);
        out[base + IMG_HW]     = fminf(fmaxf(G, 0.f), 255.f) * (1.0f / 255.0f);
        out[base + 2 * IMG_HW] = fminf(fmaxf(B, 0.f), 255.f) * (1.0f / 255.0f);
    }
}

extern "C" void kernel_launch(void* const* d_in, const int* in_sizes, int n_in,
                              void* d_out, int out_size, void* d_ws, size_t ws_size,
                              hipStream_t stream) {
    const float* yq  = (const float*)d_in[0];
    const float* cbq = (const float*)d_in[1];
    const float* crq = (const float*)d_in[2];
    const float* fac = (const float*)d_in[3];
    float* out = (float*)d_out;

    // B from flat size assuming fixed h=w=1024 (128*128 blocks * 64 coeffs)
    const int B = in_sizes[0] / (16384 * 64);

    dim3 grid(64 * 64, B);
    hipLaunchKernelGGL(jpeg_decode_kernel, grid, dim3(256), 0, stream,
                       yq, cbq, crq, fac, out);
}

// Round 2
// 72.060 us; speedup vs baseline: 2.0503x; 2.0503x over previous
//
#include <hip/hip_runtime.h>

// Fused JPEG decompress v2: row-per-lane separable IDCT.
// Workgroup = 192 threads (3 waves) handles a 64x16-pixel region:
//   wave 0: Y blocks row 2*ry,   cols rx*8..rx*8+7   (8 blocks)
//   wave 1: Y blocks row 2*ry+1, cols rx*8..rx*8+7   (8 blocks)
//   wave 2: 4 Cb + 4 Cr blocks covering the region's chroma (8 blocks)
// Each lane owns one full block row (8 floats in registers).
// Stage A (contract over y) is fully in-lane with compile-time cos literals.
// Stage B (contract over x) exchanges via a per-wave LDS slice.
// One chroma-publish barrier pair; color convert + clip + /255 fused.

#define IMG_W 1024
#define IMG_HW (1024 * 1024)

// COS[x*8+u] = cos((2u+1)*x*pi/16)
#define COS_TABLE_INIT { \
    1.0f,          1.0f,          1.0f,          1.0f,          1.0f,          1.0f,          1.0f,          1.0f, \
    0.980785280f,  0.831469612f,  0.555570233f,  0.195090322f, -0.195090322f, -0.555570233f, -0.831469612f, -0.980785280f, \
    0.923879533f,  0.382683432f, -0.382683432f, -0.923879533f, -0.923879533f, -0.382683432f,  0.382683432f,  0.923879533f, \
    0.831469612f, -0.195090322f, -0.980785280f, -0.555570233f,  0.555570233f,  0.980785280f,  0.195090322f, -0.831469612f, \
    0.707106781f, -0.707106781f, -0.707106781f,  0.707106781f,  0.707106781f, -0.707106781f, -0.707106781f,  0.707106781f, \
    0.555570233f, -0.980785280f,  0.195090322f,  0.831469612f, -0.831469612f, -0.195090322f,  0.980785280f, -0.555570233f, \
    0.382683432f, -0.923879533f,  0.923879533f, -0.382683432f, -0.382683432f,  0.923879533f, -0.923879533f,  0.382683432f, \
    0.195090322f, -0.555570233f,  0.831469612f, -0.980785280f,  0.980785280f, -0.831469612f,  0.555570233f, -0.195090322f }

static constexpr float COS_LIT[64] = COS_TABLE_INIT;  // folded to immediates in unrolled code
__constant__ float COS8C[64] = COS_TABLE_INIT;         // lane-indexed (cu) copy

__constant__ float YTAB[64] = {
    16, 11, 10, 16, 24, 40, 51, 61,
    12, 12, 14, 19, 26, 58, 60, 55,
    14, 13, 16, 24, 40, 57, 69, 56,
    14, 17, 22, 29, 51, 87, 80, 62,
    18, 22, 37, 56, 68, 109, 103, 77,
    24, 35, 55, 64, 81, 104, 113, 92,
    49, 64, 78, 87, 103, 121, 120, 101,
    72, 92, 95, 98, 112, 100, 103, 99};

__constant__ float CTAB[64] = {
    17, 18, 24, 47, 99, 99, 99, 99,
    18, 21, 26, 66, 99, 99, 99, 99,
    24, 26, 56, 99, 99, 99, 99, 99,
    47, 66, 99, 99, 99, 99, 99, 99,
    99, 99, 99, 99, 99, 99, 99, 99,
    99, 99, 99, 99, 99, 99, 99, 99,
    99, 99, 99, 99, 99, 99, 99, 99,
    99, 99, 99, 99, 99, 99, 99, 99};

__global__ __launch_bounds__(192) void jpeg_decode_kernel(
    const float* __restrict__ yq, const float* __restrict__ cbq,
    const float* __restrict__ crq, const float* __restrict__ fac,
    float* __restrict__ out)
{
    __shared__ float t1s[3][8][8][8];   // [wave][x][blk][v] stage-A exchange
    __shared__ float cpx[2][8][32];     // [plane][crow][ccol] chroma pixels (no +128)

    const int t   = threadIdx.x;
    const int w   = t >> 6;       // wave id 0..2
    const int l   = t & 63;
    const int blk = l >> 3;       // block slot 0..7 within wave
    const int row = l & 7;        // row within block (x for stage A, u for output)

    const int gid = blockIdx.x;
    const int rx  = gid & 15;          // region col (64 px each)
    const int ry  = (gid >> 4) & 63;   // region row (16 px each)
    const int img = gid >> 10;

    const float factor = fac[0];

    // ---- per-lane source row address + quant table ----
    const float* src;
    const float* qt;
    size_t base;
    if (w < 2) {
        const int nb = (ry * 2 + w) * 128 + rx * 8 + blk;   // Y block in 128x128 grid
        base = ((size_t)(img * 16384 + nb) << 6) + row * 8;
        src = yq;  qt = YTAB;
    } else {
        const int plane = blk >> 2, c = blk & 3;            // 0..3 Cb, 4..7 Cr
        const int nc = ry * 64 + rx * 4 + c;                // chroma block in 64x64 grid
        base = ((size_t)(img * 4096 + nc) << 6) + row * 8;
        src = plane ? crq : cbq;  qt = CTAB;
    }

    const float4 r0 = *reinterpret_cast<const float4*>(src + base);
    const float4 r1 = *reinterpret_cast<const float4*>(src + base + 4);

    // ---- dequant: fold 0.25 * alpha_x * alpha_y * table * factor ----
    const float ax = (row == 0) ? 0.70710678118654752f : 1.0f;
    const float s  = 0.25f * ax * factor;
    float cf[8];
    {
        float qv[8];
#pragma unroll
        for (int j = 0; j < 8; ++j) {
            const float ay = (j == 0) ? 0.70710678118654752f : 1.0f;
            qv[j] = qt[row * 8 + j] * (s * ay);
        }
        cf[0] = r0.x * qv[0]; cf[1] = r0.y * qv[1]; cf[2] = r0.z * qv[2]; cf[3] = r0.w * qv[3];
        cf[4] = r1.x * qv[4]; cf[5] = r1.y * qv[5]; cf[6] = r1.z * qv[6]; cf[7] = r1.w * qv[7];
    }

    // cu[x] = cos[x][u] for stage B (lane-dependent, loaded once)
    float cu[8];
#pragma unroll
    for (int x = 0; x < 8; ++x) cu[x] = COS8C[x * 8 + row];

    // ---- stage A (in-lane): t1[v] = sum_y cf[y] * cos[y][v], cos = literals ----
    float t1[8];
#pragma unroll
    for (int v = 0; v < 8; ++v) {
        float a = cf[0];  // cos[0][v] == 1
#pragma unroll
        for (int y = 1; y < 8; ++y) a += cf[y] * COS_LIT[y * 8 + v];
        t1[v] = a;
    }
    *reinterpret_cast<float4*>(&t1s[w][row][blk][0]) = make_float4(t1[0], t1[1], t1[2], t1[3]);
    *reinterpret_cast<float4*>(&t1s[w][row][blk][4]) = make_float4(t1[4], t1[5], t1[6], t1[7]);

    __syncthreads();

    // ---- stage B: px[v] = sum_x cu[x] * t1[x][v]  (reads own wave's slice) ----
    float px[8] = {0.f, 0.f, 0.f, 0.f, 0.f, 0.f, 0.f, 0.f};
#pragma unroll
    for (int x = 0; x < 8; ++x) {
        const float4 a = *reinterpret_cast<const float4*>(&t1s[w][x][blk][0]);
        const float4 b = *reinterpret_cast<const float4*>(&t1s[w][x][blk][4]);
        px[0] += cu[x] * a.x; px[1] += cu[x] * a.y; px[2] += cu[x] * a.z; px[3] += cu[x] * a.w;
        px[4] += cu[x] * b.x; px[5] += cu[x] * b.y; px[6] += cu[x] * b.z; px[7] += cu[x] * b.w;
    }

    // ---- chroma wave publishes its pixels (omit +128; cancels color shift) ----
    if (w == 2) {
        const int plane = blk >> 2, c = blk & 3;
        *reinterpret_cast<float4*>(&cpx[plane][row][c * 8])     = make_float4(px[0], px[1], px[2], px[3]);
        *reinterpret_cast<float4*>(&cpx[plane][row][c * 8 + 4]) = make_float4(px[4], px[5], px[6], px[7]);
    }
    __syncthreads();
    if (w == 2) return;

    // ---- Y waves: upsample chroma + color convert + clip + /255 + store ----
    const int crow = w * 4 + (row >> 1);
    const float4 cb4 = *reinterpret_cast<const float4*>(&cpx[0][crow][blk * 4]);
    const float4 cr4 = *reinterpret_cast<const float4*>(&cpx[1][crow][blk * 4]);
    const float cbv[4] = {cb4.x, cb4.y, cb4.z, cb4.w};
    const float crv[4] = {cr4.x, cr4.y, cr4.z, cr4.w};

    float R[8], G[8], Bc[8];
#pragma unroll
    for (int j = 0; j < 8; ++j) {
        const float yv = px[j] + 128.0f;
        const float cb = cbv[j >> 1], cr = crv[j >> 1];
        R[j]  = yv + 1.402f * cr;
        G[j]  = yv - 0.344136f * cb - 0.714136f * cr;
        Bc[j] = yv + 1.772f * cb;
    }
#pragma unroll
    for (int j = 0; j < 8; ++j) {
        R[j]  = fminf(fmaxf(R[j],  0.f), 255.f) * (1.0f / 255.0f);
        G[j]  = fminf(fmaxf(G[j],  0.f), 255.f) * (1.0f / 255.0f);
        Bc[j] = fminf(fmaxf(Bc[j], 0.f), 255.f) * (1.0f / 255.0f);
    }

    const int gy = (ry * 2 + w) * 8 + row;
    const int gx = rx * 64 + blk * 8;
    float* o = out + (size_t)img * 3 * IMG_HW + (size_t)gy * IMG_W + gx;

    *reinterpret_cast<float4*>(o)                  = make_float4(R[0], R[1], R[2], R[3]);
    *reinterpret_cast<float4*>(o + 4)              = make_float4(R[4], R[5], R[6], R[7]);
    *reinterpret_cast<float4*>(o + IMG_HW)         = make_float4(G[0], G[1], G[2], G[3]);
    *reinterpret_cast<float4*>(o + IMG_HW + 4)     = make_float4(G[4], G[5], G[6], G[7]);
    *reinterpret_cast<float4*>(o + 2 * IMG_HW)     = make_float4(Bc[0], Bc[1], Bc[2], Bc[3]);
    *reinterpret_cast<float4*>(o + 2 * IMG_HW + 4) = make_float4(Bc[4], Bc[5], Bc[6], Bc[7]);
}

extern "C" void kernel_launch(void* const* d_in, const int* in_sizes, int n_in,
                              void* d_out, int out_size, void* d_ws, size_t ws_size,
                              hipStream_t stream) {
    const float* yq  = (const float*)d_in[0];
    const float* cbq = (const float*)d_in[1];
    const float* crq = (const float*)d_in[2];
    const float* fac = (const float*)d_in[3];
    float* out = (float*)d_out;

    const int B = in_sizes[0] / (16384 * 64);   // 16 for the fixed 1024x1024 shape

    dim3 grid(16 * 64 * B);                     // 1024 regions per image
    hipLaunchKernelGGL(jpeg_decode_kernel, grid, dim3(192), 0, stream,
                       yq, cbq, crq, fac, out);
}

// Round 4
// 49.481 us; speedup vs baseline: 2.9859x; 1.4563x over previous
//
#include <hip/hip_runtime.h>

// Fused JPEG decompress v3b: row-per-lane IDCT + dense nontemporal stores.
// Workgroup = 192 threads (3 waves) per 64x16-pixel region:
//   wave 0/1: 8 Y blocks each; wave 2: 4 Cb + 4 Cr blocks.
// Load + stage A use lane = (blk, row). Stage B + store use lane = (r4, c):
// lane computes pixel chunk [4c..4c+3] of region rows r4 and r4+4, so each
// store instruction writes 4 fully-dense 256-B row segments (NT-safe).

#define IMG_W 1024
#define IMG_HW (1024 * 1024)

typedef float v4f __attribute__((ext_vector_type(4)));  // NT-store-compatible

// COS[x*8+u] = cos((2u+1)*x*pi/16)  (x-major; folded to FMA literals)
static constexpr float COS_LIT[64] = {
    1.0f,          1.0f,          1.0f,          1.0f,          1.0f,          1.0f,          1.0f,          1.0f,
    0.980785280f,  0.831469612f,  0.555570233f,  0.195090322f, -0.195090322f, -0.555570233f, -0.831469612f, -0.980785280f,
    0.923879533f,  0.382683432f, -0.382683432f, -0.923879533f, -0.923879533f, -0.382683432f,  0.382683432f,  0.923879533f,
    0.831469612f, -0.195090322f, -0.980785280f, -0.555570233f,  0.555570233f,  0.980785280f,  0.195090322f, -0.831469612f,
    0.707106781f, -0.707106781f, -0.707106781f,  0.707106781f,  0.707106781f, -0.707106781f, -0.707106781f,  0.707106781f,
    0.555570233f, -0.980785280f,  0.195090322f,  0.831469612f, -0.831469612f, -0.195090322f,  0.980785280f, -0.555570233f,
    0.382683432f, -0.923879533f,  0.923879533f, -0.382683432f, -0.382683432f,  0.923879533f, -0.923879533f,  0.382683432f,
    0.195090322f, -0.555570233f,  0.831469612f, -0.980785280f,  0.980785280f, -0.831469612f,  0.555570233f, -0.195090322f};

// COST[u*8+x] = cos((2u+1)*x*pi/16)  (u-major; per-lane float4 loads)
__constant__ float COST[64] = {
    1.0f,  0.980785280f,  0.923879533f,  0.831469612f,  0.707106781f,  0.555570233f,  0.382683432f,  0.195090322f,
    1.0f,  0.831469612f,  0.382683432f, -0.195090322f, -0.707106781f, -0.980785280f, -0.923879533f, -0.555570233f,
    1.0f,  0.555570233f, -0.382683432f, -0.980785280f, -0.707106781f,  0.195090322f,  0.923879533f,  0.831469612f,
    1.0f,  0.195090322f, -0.923879533f, -0.555570233f,  0.707106781f,  0.831469612f, -0.382683432f, -0.980785280f,
    1.0f, -0.195090322f, -0.923879533f,  0.555570233f,  0.707106781f, -0.831469612f, -0.382683432f,  0.980785280f,
    1.0f, -0.555570233f, -0.382683432f,  0.980785280f, -0.707106781f, -0.195090322f,  0.923879533f, -0.831469612f,
    1.0f, -0.831469612f,  0.382683432f,  0.195090322f, -0.707106781f,  0.980785280f, -0.923879533f,  0.555570233f,
    1.0f, -0.980785280f,  0.923879533f, -0.831469612f,  0.707106781f, -0.555570233f,  0.382683432f, -0.195090322f};

__constant__ float YTAB[64] = {
    16, 11, 10, 16, 24, 40, 51, 61,
    12, 12, 14, 19, 26, 58, 60, 55,
    14, 13, 16, 24, 40, 57, 69, 56,
    14, 17, 22, 29, 51, 87, 80, 62,
    18, 22, 37, 56, 68, 109, 103, 77,
    24, 35, 55, 64, 81, 104, 113, 92,
    49, 64, 78, 87, 103, 121, 120, 101,
    72, 92, 95, 98, 112, 100, 103, 99};

__constant__ float CTAB[64] = {
    17, 18, 24, 47, 99, 99, 99, 99,
    18, 21, 26, 66, 99, 99, 99, 99,
    24, 26, 56, 99, 99, 99, 99, 99,
    47, 66, 99, 99, 99, 99, 99, 99,
    99, 99, 99, 99, 99, 99, 99, 99,
    99, 99, 99, 99, 99, 99, 99, 99,
    99, 99, 99, 99, 99, 99, 99, 99,
    99, 99, 99, 99, 99, 99, 99, 99};

__global__ __launch_bounds__(192) void jpeg_decode_kernel(
    const float* __restrict__ yq, const float* __restrict__ cbq,
    const float* __restrict__ crq, const float* __restrict__ fac,
    float* __restrict__ out)
{
    __shared__ float t1s[3][8][68];   // [wave][x][blk*8+v], 68-float skew kills write conflicts
    __shared__ float cpx[2][8][32];   // [plane][crow][ccol] chroma pixels (no +128)

    const int t   = threadIdx.x;
    const int w   = t >> 6;
    const int l   = t & 63;
    const int blk = l >> 3;     // load/stage-A: block slot
    const int row = l & 7;      // load/stage-A: row (x) within block

    const int gid = blockIdx.x;
    const int rx  = gid & 15;
    const int ry  = (gid >> 4) & 63;
    const int img = gid >> 10;

    const float factor = fac[0];

    // ---- per-lane source row load ----
    const float* src;
    const float* qt;
    size_t base;
    if (w < 2) {
        const int nb = (ry * 2 + w) * 128 + rx * 8 + blk;
        base = ((size_t)(img * 16384 + nb) << 6) + row * 8;
        src = yq;  qt = YTAB;
    } else {
        const int nc = ry * 64 + rx * 4 + (blk & 3);
        base = ((size_t)(img * 4096 + nc) << 6) + row * 8;
        src = (blk & 4) ? crq : cbq;  qt = CTAB;
    }
    const float4 r0 = *reinterpret_cast<const float4*>(src + base);
    const float4 r1 = *reinterpret_cast<const float4*>(src + base + 4);
    const float4 q0 = *reinterpret_cast<const float4*>(qt + row * 8);
    const float4 q1 = *reinterpret_cast<const float4*>(qt + row * 8 + 4);

    // ---- dequant: fold 0.25 * alpha_x * alpha_y * factor ----
    const float s = 0.25f * factor * ((row == 0) ? 0.70710678118654752f : 1.0f);
    float cf[8];
    cf[0] = r0.x * (q0.x * (s * 0.70710678118654752f));
    cf[1] = r0.y * (q0.y * s);
    cf[2] = r0.z * (q0.z * s);
    cf[3] = r0.w * (q0.w * s);
    cf[4] = r1.x * (q1.x * s);
    cf[5] = r1.y * (q1.y * s);
    cf[6] = r1.z * (q1.z * s);
    cf[7] = r1.w * (q1.w * s);

    // ---- stage A (in-lane, literal cosines): t1[v] = sum_y cf[y]*cos[y][v] ----
    float t1[8];
#pragma unroll
    for (int v = 0; v < 8; ++v) {
        float a = cf[0];
#pragma unroll
        for (int y = 1; y < 8; ++y) a += cf[y] * COS_LIT[y * 8 + v];
        t1[v] = a;
    }
    *reinterpret_cast<float4*>(&t1s[w][row][blk * 8])     = make_float4(t1[0], t1[1], t1[2], t1[3]);
    *reinterpret_cast<float4*>(&t1s[w][row][blk * 8 + 4]) = make_float4(t1[4], t1[5], t1[6], t1[7]);
    // stage A -> B exchange is intra-wave only: DS ops from one wave complete
    // in order, compiler inserts lgkmcnt waits -> no barrier needed here.

    // ---- stage B mapping: lane = (r4, c); chunk c of rows r4 and r4+4 ----
    const int r4 = l >> 4;      // 0..3
    const int c  = l & 15;      // 16-B chunk within 64-px row
    float cuA[8], cuB[8];
    {
        const float4 a0 = *reinterpret_cast<const float4*>(&COST[r4 * 8]);
        const float4 a1 = *reinterpret_cast<const float4*>(&COST[r4 * 8 + 4]);
        const float4 b0 = *reinterpret_cast<const float4*>(&COST[(r4 + 4) * 8]);
        const float4 b1 = *reinterpret_cast<const float4*>(&COST[(r4 + 4) * 8 + 4]);
        cuA[0]=a0.x; cuA[1]=a0.y; cuA[2]=a0.z; cuA[3]=a0.w;
        cuA[4]=a1.x; cuA[5]=a1.y; cuA[6]=a1.z; cuA[7]=a1.w;
        cuB[0]=b0.x; cuB[1]=b0.y; cuB[2]=b0.z; cuB[3]=b0.w;
        cuB[4]=b1.x; cuB[5]=b1.y; cuB[6]=b1.z; cuB[7]=b1.w;
    }

    float pA[4] = {0.f, 0.f, 0.f, 0.f};
    float pB[4] = {0.f, 0.f, 0.f, 0.f};
#pragma unroll
    for (int x = 0; x < 8; ++x) {
        const float4 v = *reinterpret_cast<const float4*>(&t1s[w][x][c * 4]);
        pA[0] += cuA[x] * v.x; pA[1] += cuA[x] * v.y; pA[2] += cuA[x] * v.z; pA[3] += cuA[x] * v.w;
        pB[0] += cuB[x] * v.x; pB[1] += cuB[x] * v.y; pB[2] += cuB[x] * v.z; pB[3] += cuB[x] * v.w;
    }

    // ---- chroma wave publishes (omit +128; cancels color shift) ----
    if (w == 2) {
        const int pl  = c >> 3;          // plane
        const int col = (c * 4) & 31;    // chroma col within 32-wide region
        *reinterpret_cast<float4*>(&cpx[pl][r4][col])     = make_float4(pA[0], pA[1], pA[2], pA[3]);
        *reinterpret_cast<float4*>(&cpx[pl][r4 + 4][col]) = make_float4(pB[0], pB[1], pB[2], pB[3]);
    }
    __syncthreads();
    if (w == 2) return;

    // ---- Y waves: upsample + color convert + clip + /255 + dense NT stores ----
    const int crA = w * 4 + (r4 >> 1);   // chroma row for region row w*8+r4
    const int crB = crA + 2;             // for region row w*8+r4+4
    const float2 cbA = *reinterpret_cast<const float2*>(&cpx[0][crA][c * 2]);
    const float2 crA2 = *reinterpret_cast<const float2*>(&cpx[1][crA][c * 2]);
    const float2 cbB = *reinterpret_cast<const float2*>(&cpx[0][crB][c * 2]);
    const float2 crB2 = *reinterpret_cast<const float2*>(&cpx[1][crB][c * 2]);

    const int gyA = (ry * 2 + w) * 8 + r4;
    const int gx  = rx * 64 + c * 4;
    float* o = out + (size_t)img * 3 * IMG_HW + (size_t)gyA * IMG_W + gx;

    auto convert4 = [&](const float p[4], float2 cb2, float2 cr2, float* dst) {
        float R[4], G[4], Bv[4];
#pragma unroll
        for (int j = 0; j < 4; ++j) {
            const float yv = p[j] + 128.0f;
            const float cb = (j < 2) ? cb2.x : cb2.y;
            const float cr = (j < 2) ? cr2.x : cr2.y;
            R[j]  = yv + 1.402f * cr;
            G[j]  = yv - 0.344136f * cb - 0.714136f * cr;
            Bv[j] = yv + 1.772f * cb;
        }
#pragma unroll
        for (int j = 0; j < 4; ++j) {
            R[j]  = fminf(fmaxf(R[j],  0.f), 255.f) * (1.0f / 255.0f);
            G[j]  = fminf(fmaxf(G[j],  0.f), 255.f) * (1.0f / 255.0f);
            Bv[j] = fminf(fmaxf(Bv[j], 0.f), 255.f) * (1.0f / 255.0f);
        }
        v4f rv = {R[0], R[1], R[2], R[3]};
        v4f gv = {G[0], G[1], G[2], G[3]};
        v4f bv = {Bv[0], Bv[1], Bv[2], Bv[3]};
        __builtin_nontemporal_store(rv, reinterpret_cast<v4f*>(dst));
        __builtin_nontemporal_store(gv, reinterpret_cast<v4f*>(dst + IMG_HW));
        __builtin_nontemporal_store(bv, reinterpret_cast<v4f*>(dst + 2 * IMG_HW));
    };
    convert4(pA, cbA, crA2, o);
    convert4(pB, cbB, crB2, o + 4 * IMG_W);
}

extern "C" void kernel_launch(void* const* d_in, const int* in_sizes, int n_in,
                              void* d_out, int out_size, void* d_ws, size_t ws_size,
                              hipStream_t stream) {
    const float* yq  = (const float*)d_in[0];
    const float* cbq = (const float*)d_in[1];
    const float* crq = (const float*)d_in[2];
    const float* fac = (const float*)d_in[3];
    float* out = (float*)d_out;

    const int B = in_sizes[0] / (16384 * 64);

    dim3 grid(1024 * B);
    hipLaunchKernelGGL(jpeg_decode_kernel, grid, dim3(192), 0, stream,
                       yq, cbq, crq, fac, out);
}

// Round 5
// 48.978 us; speedup vs baseline: 3.0166x; 1.0103x over previous
//
#include <hip/hip_runtime.h>

// Fused JPEG decompress v4: row-per-lane IDCT + dense NT stores, store phase
// balanced across all 3 waves. Workgroup = 192 threads per 64x16-px region:
//   wave 0/1: 8 Y blocks each; wave 2: 4 Cb + 4 Cr blocks.
// After IDCT, Y waves publish pixels to LDS; post-barrier, Y waves store the
// R and G planes (4 NT stores/lane) and wave 2 stores the B plane
// (4 NT stores/lane) -> uniform 4 stores/lane across the block.

#define IMG_W 1024
#define IMG_HW (1024 * 1024)

typedef float v4f __attribute__((ext_vector_type(4)));

// COS[x*8+u] = cos((2u+1)*x*pi/16)  (x-major; folded to FMA literals)
static constexpr float COS_LIT[64] = {
    1.0f,          1.0f,          1.0f,          1.0f,          1.0f,          1.0f,          1.0f,          1.0f,
    0.980785280f,  0.831469612f,  0.555570233f,  0.195090322f, -0.195090322f, -0.555570233f, -0.831469612f, -0.980785280f,
    0.923879533f,  0.382683432f, -0.382683432f, -0.923879533f, -0.923879533f, -0.382683432f,  0.382683432f,  0.923879533f,
    0.831469612f, -0.195090322f, -0.980785280f, -0.555570233f,  0.555570233f,  0.980785280f,  0.195090322f, -0.831469612f,
    0.707106781f, -0.707106781f, -0.707106781f,  0.707106781f,  0.707106781f, -0.707106781f, -0.707106781f,  0.707106781f,
    0.555570233f, -0.980785280f,  0.195090322f,  0.831469612f, -0.831469612f, -0.195090322f,  0.980785280f, -0.555570233f,
    0.382683432f, -0.923879533f,  0.923879533f, -0.382683432f, -0.382683432f,  0.923879533f, -0.923879533f,  0.382683432f,
    0.195090322f, -0.555570233f,  0.831469612f, -0.980785280f,  0.980785280f, -0.831469612f,  0.555570233f, -0.195090322f};

// COST[u*8+x] = cos((2u+1)*x*pi/16)  (u-major; per-lane float4 loads)
__constant__ float COST[64] = {
    1.0f,  0.980785280f,  0.923879533f,  0.831469612f,  0.707106781f,  0.555570233f,  0.382683432f,  0.195090322f,
    1.0f,  0.831469612f,  0.382683432f, -0.195090322f, -0.707106781f, -0.980785280f, -0.923879533f, -0.555570233f,
    1.0f,  0.555570233f, -0.382683432f, -0.980785280f, -0.707106781f,  0.195090322f,  0.923879533f,  0.831469612f,
    1.0f,  0.195090322f, -0.923879533f, -0.555570233f,  0.707106781f,  0.831469612f, -0.382683432f, -0.980785280f,
    1.0f, -0.195090322f, -0.923879533f,  0.555570233f,  0.707106781f, -0.831469612f, -0.382683432f,  0.980785280f,
    1.0f, -0.555570233f, -0.382683432f,  0.980785280f, -0.707106781f, -0.195090322f,  0.923879533f, -0.831469612f,
    1.0f, -0.831469612f,  0.382683432f,  0.195090322f, -0.707106781f,  0.980785280f, -0.923879533f,  0.555570233f,
    1.0f, -0.980785280f,  0.923879533f, -0.831469612f,  0.707106781f, -0.555570233f,  0.382683432f, -0.195090322f};

__constant__ float YTAB[64] = {
    16, 11, 10, 16, 24, 40, 51, 61,
    12, 12, 14, 19, 26, 58, 60, 55,
    14, 13, 16, 24, 40, 57, 69, 56,
    14, 17, 22, 29, 51, 87, 80, 62,
    18, 22, 37, 56, 68, 109, 103, 77,
    24, 35, 55, 64, 81, 104, 113, 92,
    49, 64, 78, 87, 103, 121, 120, 101,
    72, 92, 95, 98, 112, 100, 103, 99};

__constant__ float CTAB[64] = {
    17, 18, 24, 47, 99, 99, 99, 99,
    18, 21, 26, 66, 99, 99, 99, 99,
    24, 26, 56, 99, 99, 99, 99, 99,
    47, 66, 99, 99, 99, 99, 99, 99,
    99, 99, 99, 99, 99, 99, 99, 99,
    99, 99, 99, 99, 99, 99, 99, 99,
    99, 99, 99, 99, 99, 99, 99, 99,
    99, 99, 99, 99, 99, 99, 99, 99};

__global__ __launch_bounds__(192) void jpeg_decode_kernel(
    const float* __restrict__ yq, const float* __restrict__ cbq,
    const float* __restrict__ crq, const float* __restrict__ fac,
    float* __restrict__ out)
{
    __shared__ float t1s[3][8][68];   // [wave][x][blk*8+v], skewed
    __shared__ float ys[16][68];      // Y pixels (no +128), skewed
    __shared__ float cpx[2][8][32];   // chroma pixels (no +128)

    const int t   = threadIdx.x;
    const int w   = t >> 6;
    const int l   = t & 63;
    const int blk = l >> 3;     // load/stage-A: block slot
    const int row = l & 7;      // load/stage-A: row (x) within block

    const int gid = blockIdx.x;
    const int rx  = gid & 15;
    const int ry  = (gid >> 4) & 63;
    const int img = gid >> 10;

    const float factor = fac[0];

    // ---- per-lane source row load ----
    const float* src;
    const float* qt;
    size_t base;
    if (w < 2) {
        const int nb = (ry * 2 + w) * 128 + rx * 8 + blk;
        base = ((size_t)(img * 16384 + nb) << 6) + row * 8;
        src = yq;  qt = YTAB;
    } else {
        const int nc = ry * 64 + rx * 4 + (blk & 3);
        base = ((size_t)(img * 4096 + nc) << 6) + row * 8;
        src = (blk & 4) ? crq : cbq;  qt = CTAB;
    }
    const float4 r0 = *reinterpret_cast<const float4*>(src + base);
    const float4 r1 = *reinterpret_cast<const float4*>(src + base + 4);
    const float4 q0 = *reinterpret_cast<const float4*>(qt + row * 8);
    const float4 q1 = *reinterpret_cast<const float4*>(qt + row * 8 + 4);

    // ---- dequant: fold 0.25 * alpha_x * alpha_y * factor ----
    const float s = 0.25f * factor * ((row == 0) ? 0.70710678118654752f : 1.0f);
    float cf[8];
    cf[0] = r0.x * (q0.x * (s * 0.70710678118654752f));
    cf[1] = r0.y * (q0.y * s);
    cf[2] = r0.z * (q0.z * s);
    cf[3] = r0.w * (q0.w * s);
    cf[4] = r1.x * (q1.x * s);
    cf[5] = r1.y * (q1.y * s);
    cf[6] = r1.z * (q1.z * s);
    cf[7] = r1.w * (q1.w * s);

    // ---- stage A (in-lane, literal cosines): t1[v] = sum_y cf[y]*cos[y][v] ----
    float t1[8];
#pragma unroll
    for (int v = 0; v < 8; ++v) {
        float a = cf[0];
#pragma unroll
        for (int y = 1; y < 8; ++y) a += cf[y] * COS_LIT[y * 8 + v];
        t1[v] = a;
    }
    *reinterpret_cast<float4*>(&t1s[w][row][blk * 8])     = make_float4(t1[0], t1[1], t1[2], t1[3]);
    *reinterpret_cast<float4*>(&t1s[w][row][blk * 8 + 4]) = make_float4(t1[4], t1[5], t1[6], t1[7]);
    // stage A -> B exchange is intra-wave only (DS ops in-order per wave).

    // ---- stage B mapping: lane = (r4, c); chunk c of rows r4 and r4+4 ----
    const int r4 = l >> 4;      // 0..3
    const int c  = l & 15;      // 16-B chunk within 64-px row
    float cuA[8], cuB[8];
    {
        const float4 a0 = *reinterpret_cast<const float4*>(&COST[r4 * 8]);
        const float4 a1 = *reinterpret_cast<const float4*>(&COST[r4 * 8 + 4]);
        const float4 b0 = *reinterpret_cast<const float4*>(&COST[(r4 + 4) * 8]);
        const float4 b1 = *reinterpret_cast<const float4*>(&COST[(r4 + 4) * 8 + 4]);
        cuA[0]=a0.x; cuA[1]=a0.y; cuA[2]=a0.z; cuA[3]=a0.w;
        cuA[4]=a1.x; cuA[5]=a1.y; cuA[6]=a1.z; cuA[7]=a1.w;
        cuB[0]=b0.x; cuB[1]=b0.y; cuB[2]=b0.z; cuB[3]=b0.w;
        cuB[4]=b1.x; cuB[5]=b1.y; cuB[6]=b1.z; cuB[7]=b1.w;
    }

    float pA[4] = {0.f, 0.f, 0.f, 0.f};
    float pB[4] = {0.f, 0.f, 0.f, 0.f};
#pragma unroll
    for (int x = 0; x < 8; ++x) {
        const float4 v = *reinterpret_cast<const float4*>(&t1s[w][x][c * 4]);
        pA[0] += cuA[x] * v.x; pA[1] += cuA[x] * v.y; pA[2] += cuA[x] * v.z; pA[3] += cuA[x] * v.w;
        pB[0] += cuB[x] * v.x; pB[1] += cuB[x] * v.y; pB[2] += cuB[x] * v.z; pB[3] += cuB[x] * v.w;
    }

    // ---- publish: Y waves -> ys, chroma wave -> cpx (all without +128) ----
    if (w < 2) {
        *reinterpret_cast<float4*>(&ys[w * 8 + r4][c * 4])     = make_float4(pA[0], pA[1], pA[2], pA[3]);
        *reinterpret_cast<float4*>(&ys[w * 8 + r4 + 4][c * 4]) = make_float4(pB[0], pB[1], pB[2], pB[3]);
    } else {
        const int pl  = c >> 3;
        const int col = (c * 4) & 31;
        *reinterpret_cast<float4*>(&cpx[pl][r4][col])     = make_float4(pA[0], pA[1], pA[2], pA[3]);
        *reinterpret_cast<float4*>(&cpx[pl][r4 + 4][col]) = make_float4(pB[0], pB[1], pB[2], pB[3]);
    }
    __syncthreads();

    const int gx = rx * 64 + c * 4;
    float* const obase = out + (size_t)img * 3 * IMG_HW + gx;

    if (w < 2) {
        // ---- Y waves: R and G planes for rows w*8+r4 and w*8+r4+4 ----
        const int crA = w * 4 + (r4 >> 1);
        const int crB = crA + 2;
        const float2 cbA  = *reinterpret_cast<const float2*>(&cpx[0][crA][c * 2]);
        const float2 crA2 = *reinterpret_cast<const float2*>(&cpx[1][crA][c * 2]);
        const float2 cbB  = *reinterpret_cast<const float2*>(&cpx[0][crB][c * 2]);
        const float2 crB2 = *reinterpret_cast<const float2*>(&cpx[1][crB][c * 2]);

        const int gyA = (ry * 2 + w) * 8 + r4;
        float* o = obase + (size_t)gyA * IMG_W;

        auto storeRG = [&](const float p[4], float2 cb2, float2 cr2, float* dst) {
            float R[4], G[4];
#pragma unroll
            for (int j = 0; j < 4; ++j) {
                const float yv = p[j] + 128.0f;
                const float cb = (j < 2) ? cb2.x : cb2.y;
                const float cr = (j < 2) ? cr2.x : cr2.y;
                R[j] = yv + 1.402f * cr;
                G[j] = yv - 0.344136f * cb - 0.714136f * cr;
            }
#pragma unroll
            for (int j = 0; j < 4; ++j) {
                R[j] = fminf(fmaxf(R[j], 0.f), 255.f) * (1.0f / 255.0f);
                G[j] = fminf(fmaxf(G[j], 0.f), 255.f) * (1.0f / 255.0f);
            }
            v4f rv = {R[0], R[1], R[2], R[3]};
            v4f gv = {G[0], G[1], G[2], G[3]};
            __builtin_nontemporal_store(rv, reinterpret_cast<v4f*>(dst));
            __builtin_nontemporal_store(gv, reinterpret_cast<v4f*>(dst + IMG_HW));
        };
        storeRG(pA, cbA, crA2, o);
        storeRG(pB, cbB, crB2, o + 4 * IMG_W);
    } else {
        // ---- chroma wave: B plane for all 16 rows (4 per lane) ----
#pragma unroll
        for (int i = 0; i < 4; ++i) {
            const int rrow = 4 * i + r4;                 // row within region
            const float4 y4  = *reinterpret_cast<const float4*>(&ys[rrow][c * 4]);
            const float2 cb2 = *reinterpret_cast<const float2*>(&cpx[0][rrow >> 1][c * 2]);
            float Bv[4];
            const float yv4[4] = {y4.x, y4.y, y4.z, y4.w};
#pragma unroll
            for (int j = 0; j < 4; ++j) {
                const float cb = (j < 2) ? cb2.x : cb2.y;
                Bv[j] = yv4[j] + 128.0f + 1.772f * cb;
                Bv[j] = fminf(fmaxf(Bv[j], 0.f), 255.f) * (1.0f / 255.0f);
            }
            const int gy = ry * 16 + rrow;
            v4f bv = {Bv[0], Bv[1], Bv[2], Bv[3]};
            __builtin_nontemporal_store(bv,
                reinterpret_cast<v4f*>(obase + 2 * IMG_HW + (size_t)gy * IMG_W));
        }
    }
}

extern "C" void kernel_launch(void* const* d_in, const int* in_sizes, int n_in,
                              void* d_out, int out_size, void* d_ws, size_t ws_size,
                              hipStream_t stream) {
    const float* yq  = (const float*)d_in[0];
    const float* cbq = (const float*)d_in[1];
    const float* crq = (const float*)d_in[2];
    const float* fac = (const float*)d_in[3];
    float* out = (float*)d_out;

    const int B = in_sizes[0] / (16384 * 64);

    dim3 grid(1024 * B);
    hipLaunchKernelGGL(jpeg_decode_kernel, grid, dim3(192), 0, stream,
                       yq, cbq, crq, fac, out);
}